// Round 9
// baseline (121.649 us; speedup 1.0000x reference)
//
#include <hip/hip_runtime.h>
#include <hip/hip_bf16.h>

#define N_SITES 200000
#define CIN 256
#define CMID 64
#define KVOL 9

using bf16x8 = __attribute__((ext_vector_type(8))) short;
using f32x4  = __attribute__((ext_vector_type(4))) float;

__device__ __forceinline__ short f2bf(float f) {
    union { float f; unsigned u; } v; v.f = f;
    unsigned r = v.u + 0x7fffu + ((v.u >> 16) & 1u);   // RNE
    return (short)(r >> 16);
}

__device__ __forceinline__ f32x4 mfma16(bf16x8 a, bf16x8 b, f32x4 c) {
    return __builtin_amdgcn_mfma_f32_16x16x32_bf16(a, b, c, 0, 0, 0);
}

// ---------------- K1: x1 = relu(feat @ W1)  + folded W2/W3 bf16 transposition
__global__ __launch_bounds__(256) void k1_conv1(const float* __restrict__ feat,
                                                const float* __restrict__ W1,
                                                const float* __restrict__ W2,
                                                const float* __restrict__ W3,
                                                short* __restrict__ x1,
                                                short* __restrict__ W2T,
                                                short* __restrict__ W3T) {
    const int t = threadIdx.x;
    const int gt = blockIdx.x * 256 + t;
    if (gt < KVOL * CMID * CMID) {            // W2T[kk][co][k] = bf(W2[kk][k][co])
        int kk = gt >> 12, rem = gt & 4095, co = rem >> 6, k = rem & 63;
        W2T[gt] = f2bf(W2[kk * 4096 + k * 64 + co]);
    }
    if (gt < CMID * CIN) {                    // W3T[co][k] = bf(W3[k][co])
        int co = gt >> 6, k = gt & 63;
        W3T[gt] = f2bf(W3[k * 256 + co]);
    }

    __shared__ short w1t[64][264];   // W1^T
    __shared__ short o1[64][72];     // bf16 out staging
    const int lane = t & 63, w = t >> 6;
    const int r = lane & 15, g = lane >> 4;

    #pragma unroll
    for (int qq = 0; qq < 16; ++qq) {
        int k0 = 4 * w + 16 * qq;
        float v0 = W1[(k0 + 0) * 64 + lane];
        float v1 = W1[(k0 + 1) * 64 + lane];
        float v2 = W1[(k0 + 2) * 64 + lane];
        float v3 = W1[(k0 + 3) * 64 + lane];
        *(short4*)&w1t[lane][k0] = make_short4(f2bf(v0), f2bf(v1), f2bf(v2), f2bf(v3));
    }
    __syncthreads();

    const int row0 = blockIdx.x * 64 + w * 16;
    const float* ap = feat + (size_t)(row0 + r) * CIN + g * 8;

    f32x4 acc[4] = {};
    #pragma unroll
    for (int ks = 0; ks < 8; ++ks) {
        f32x4 a0 = *(const f32x4*)(ap + ks * 32);
        f32x4 a1 = *(const f32x4*)(ap + ks * 32 + 4);
        bf16x8 af;
        #pragma unroll
        for (int j = 0; j < 4; ++j) { af[j] = f2bf(a0[j]); af[4 + j] = f2bf(a1[j]); }
        #pragma unroll
        for (int ct = 0; ct < 4; ++ct) {
            bf16x8 bf = *(const bf16x8*)&w1t[ct * 16 + r][ks * 32 + g * 8];
            acc[ct] = mfma16(af, bf, acc[ct]);
        }
    }
    #pragma unroll
    for (int ct = 0; ct < 4; ++ct)
        #pragma unroll
        for (int j = 0; j < 4; ++j) {
            float v = acc[ct][j];
            o1[w * 16 + g * 4 + j][ct * 16 + r] = f2bf(v > 0.f ? v : 0.f);
        }
    __syncthreads();
    #pragma unroll
    for (int i = 0; i < 2; ++i) {
        int v = t + 256 * i; int row = v >> 3, c8 = v & 7;
        *(bf16x8*)&x1[(size_t)(blockIdx.x * 64 + row) * CMID + c8 * 8] =
            *(const bf16x8*)&o1[row][c8 * 8];
    }
}

// ---------------- K23: fused conv2+relu+conv3+residual+relu
// LDS 27.6 KB (w2t 18K dbuf; w3t 9K quarter; o2 aliases w3t; ot aliases w2t)
__global__ __launch_bounds__(256) void k23_fused(const short* __restrict__ x1,
                                                 const short* __restrict__ W2T,
                                                 const short* __restrict__ W3T,
                                                 const int* __restrict__ nbr,
                                                 const float* __restrict__ feat,
                                                 float* __restrict__ out) {
    __shared__ short w2t[2][64][72];  // 18 KB; epilogue 'ot' aliases [0]
    __shared__ short w3t[64][72];     // 9 KB, one 64-col quarter of W3T
    auto ot = reinterpret_cast<float(*)[16][36]>(&w2t[0][0][0]);  // [4][16][36] f32
    auto o2 = reinterpret_cast<short(*)[16][72]>(&w3t[0][0]);     // [4][16][72] bf16

    const int t = threadIdx.x;
    const int lane = t & 63, w = t >> 6;
    const int r = lane & 15, g = lane >> 4;

    // bijective XCD swizzle (3125 % 8 = 5)
    const int nwg = gridDim.x;
    const int q = nwg >> 3, rm = nwg & 7;
    const int xcd = blockIdx.x & 7, pos = blockIdx.x >> 3;
    const int bid = (xcd < rm) ? xcd * (q + 1) + pos
                               : rm * (q + 1) + (xcd - rm) * q + pos;

    const int row0 = bid * 64 + w * 16;
    const int site = row0 + r;

    int idx9[9];
    #pragma unroll
    for (int kk = 0; kk < 9; ++kk) idx9[kk] = nbr[site * 9 + kk];

    // stage w2t[0]: flat-contiguous 4KB-per-instr reads, balanced b128 LDS writes
    {
        const short* src = W2T + t * 8;
        bf16x8 v0 = *(const bf16x8*)(src);
        bf16x8 v1 = *(const bf16x8*)(src + 2048);
        *(bf16x8*)&w2t[0][(t >> 3)][(t & 7) * 8] = v0;
        *(bf16x8*)&w2t[0][(t >> 3) + 32][(t & 7) * 8] = v1;
    }
    // gather pipeline depth 3 (statically indexed)
    bf16x8 ga[3], gb[3];
    #pragma unroll
    for (int p = 0; p < 3; ++p) {
        ga[p] = (bf16x8){}; gb[p] = (bf16x8){};
        int ii = idx9[p];
        if (ii >= 0) { const short* gp = x1 + (size_t)ii * CMID + g * 8;
                       ga[p] = *(const bf16x8*)gp; gb[p] = *(const bf16x8*)(gp + 32); }
    }
    __syncthreads();

    f32x4 acc2[4] = {};
    #pragma unroll
    for (int kk = 0; kk < 9; ++kk) {
        const int cur = kk % 3;
        bf16x8 a0 = ga[cur], a1 = gb[cur];
        bf16x8 n0 = {}, n1 = {};
        if (kk + 3 < 9) {
            int ii = idx9[kk + 3];
            if (ii >= 0) { const short* gp = x1 + (size_t)ii * CMID + g * 8;
                           n0 = *(const bf16x8*)gp; n1 = *(const bf16x8*)(gp + 32); }
        }
        ga[cur] = n0; gb[cur] = n1;
        bf16x8 s0, s1;
        if (kk < 8) {
            const short* src = W2T + (kk + 1) * 4096 + t * 8;
            s0 = *(const bf16x8*)(src);
            s1 = *(const bf16x8*)(src + 2048);
        }
        #pragma unroll
        for (int ct = 0; ct < 4; ++ct) {
            bf16x8 b0 = *(const bf16x8*)&w2t[kk & 1][ct * 16 + r][g * 8];
            bf16x8 b1 = *(const bf16x8*)&w2t[kk & 1][ct * 16 + r][32 + g * 8];
            acc2[ct] = mfma16(a0, b0, acc2[ct]);
            acc2[ct] = mfma16(a1, b1, acc2[ct]);
        }
        if (kk < 8) {
            *(bf16x8*)&w2t[(kk & 1) ^ 1][(t >> 3)][(t & 7) * 8] = s0;
            *(bf16x8*)&w2t[(kk & 1) ^ 1][(t >> 3) + 32][(t & 7) * 8] = s1;
        }
        __syncthreads();
    }

    // x2 bounce: wave-private (o2 aliases w3t — w3t untouched so far; safe)
    #pragma unroll
    for (int ct = 0; ct < 4; ++ct)
        #pragma unroll
        for (int j = 0; j < 4; ++j) {
            float v = acc2[ct][j];
            o2[w][g * 4 + j][ct * 16 + r] = f2bf(v > 0.f ? v : 0.f);
        }
    asm volatile("s_waitcnt lgkmcnt(0)" ::: "memory");
    bf16x8 A0 = *(const bf16x8*)&o2[w][r][g * 8];
    bf16x8 A1 = *(const bf16x8*)&o2[w][r][32 + g * 8];

    // conv3 + residual + relu in four 64-col quarters
    #pragma unroll
    for (int h = 0; h < 4; ++h) {
        __syncthreads();   // h=0: every wave has A0/A1 in regs -> o2 region reusable
        // stage w3t quarter: 8KB, flat-contiguous 4KB-per-instr reads
        {
            const short* src = W3T + h * 4096 + t * 8;
            #pragma unroll
            for (int i = 0; i < 2; ++i) {
                bf16x8 u = *(const bf16x8*)(src + i * 2048);
                *(bf16x8*)&w3t[(t >> 3) + i * 32][(t & 7) * 8] = u;
            }
        }
        __syncthreads();

        f32x4 acc3[4];
        #pragma unroll
        for (int ct = 0; ct < 4; ++ct) {
            bf16x8 b0 = *(const bf16x8*)&w3t[ct * 16 + r][g * 8];
            bf16x8 b1 = *(const bf16x8*)&w3t[ct * 16 + r][32 + g * 8];
            f32x4 z = {};
            z = mfma16(A0, b0, z);
            acc3[ct] = mfma16(A1, b1, z);
        }

        // epilogue: 2 chunks of 32 cols, wave-private ot (aliases dead w2t)
        #pragma unroll
        for (int c = 0; c < 2; ++c) {
            #pragma unroll
            for (int ci = 0; ci < 2; ++ci)
                #pragma unroll
                for (int j = 0; j < 4; ++j)
                    ot[w][g * 4 + j][ci * 16 + r] = acc3[c * 2 + ci][j];
            asm volatile("s_waitcnt lgkmcnt(0)" ::: "memory");
            #pragma unroll
            for (int i = 0; i < 2; ++i) {
                int v = lane + 64 * i;
                int row = v >> 3, c4 = v & 7;
                size_t o = (size_t)(row0 + row) * CIN + h * 64 + c * 32 + c4 * 4;
                f32x4 f = *(const f32x4*)&feat[o];       // cacheable: harvest L3 from K1
                f32x4 s = *(const f32x4*)&ot[w][row][c4 * 4];
                f32x4 res;
                #pragma unroll
                for (int j = 0; j < 4; ++j) { float x = s[j] + f[j]; res[j] = x > 0.f ? x : 0.f; }
                __builtin_nontemporal_store(res, (f32x4*)&out[o]);
            }
        }
    }
}

extern "C" void kernel_launch(void* const* d_in, const int* in_sizes, int n_in,
                              void* d_out, int out_size, void* d_ws, size_t ws_size,
                              hipStream_t stream) {
    const float* feat = (const float*)d_in[0];
    const float* W1   = (const float*)d_in[1];
    const float* W2   = (const float*)d_in[2];
    const float* W3   = (const float*)d_in[3];
    const int*   nbr  = (const int*)d_in[4];

    short* x1  = (short*)d_ws;                          // [N,64] bf16, 25.6 MB
    short* W2T = x1 + (size_t)N_SITES * CMID;           // [9][64][64] bf16
    short* W3T = W2T + KVOL * CMID * CMID;              // [256][64] bf16
    float* out = (float*)d_out;

    const int blocks = N_SITES / 64;                    // 3125
    hipLaunchKernelGGL(k1_conv1, dim3(blocks), dim3(256), 0, stream,
                       feat, W1, W2, W3, x1, W2T, W3T);
    hipLaunchKernelGGL(k23_fused, dim3(blocks), dim3(256), 0, stream,
                       x1, W2T, W3T, nbr, feat, out);
}

// Round 10
// 120.525 us; speedup vs baseline: 1.0093x; 1.0093x over previous
//
#include <hip/hip_runtime.h>
#include <hip/hip_bf16.h>

#define N_SITES 200000
#define CIN 256
#define CMID 64
#define KVOL 9
#define UNITS 12500            // N_SITES / 16

using bf16x8 = __attribute__((ext_vector_type(8))) short;
using f32x4  = __attribute__((ext_vector_type(4))) float;

__device__ __forceinline__ short f2bf(float f) {
    union { float f; unsigned u; } v; v.f = f;
    unsigned r = v.u + 0x7fffu + ((v.u >> 16) & 1u);   // RNE
    return (short)(r >> 16);
}

__device__ __forceinline__ f32x4 mfma16(bf16x8 a, bf16x8 b, f32x4 c) {
    return __builtin_amdgcn_mfma_f32_16x16x32_bf16(a, b, c, 0, 0, 0);
}

// ---------------- K1: x1 = relu(feat @ W1)  + folded W2/W3 bf16 transposition
__global__ __launch_bounds__(256) void k1_conv1(const float* __restrict__ feat,
                                                const float* __restrict__ W1,
                                                const float* __restrict__ W2,
                                                const float* __restrict__ W3,
                                                short* __restrict__ x1,
                                                short* __restrict__ W2T,
                                                short* __restrict__ W3T) {
    const int t = threadIdx.x;
    const int gt = blockIdx.x * 256 + t;
    if (gt < KVOL * CMID * CMID) {            // W2T[kk][co][k] = bf(W2[kk][k][co])
        int kk = gt >> 12, rem = gt & 4095, co = rem >> 6, k = rem & 63;
        W2T[gt] = f2bf(W2[kk * 4096 + k * 64 + co]);
    }
    if (gt < CMID * CIN) {                    // W3T[co][k] = bf(W3[k][co])
        int co = gt >> 6, k = gt & 63;
        W3T[gt] = f2bf(W3[k * 256 + co]);
    }

    __shared__ short w1t[64][264];   // W1^T
    __shared__ short o1[64][72];     // bf16 out staging
    const int lane = t & 63, w = t >> 6;
    const int r = lane & 15, g = lane >> 4;

    #pragma unroll
    for (int qq = 0; qq < 16; ++qq) {
        int k0 = 4 * w + 16 * qq;
        float v0 = W1[(k0 + 0) * 64 + lane];
        float v1 = W1[(k0 + 1) * 64 + lane];
        float v2 = W1[(k0 + 2) * 64 + lane];
        float v3 = W1[(k0 + 3) * 64 + lane];
        *(short4*)&w1t[lane][k0] = make_short4(f2bf(v0), f2bf(v1), f2bf(v2), f2bf(v3));
    }
    __syncthreads();

    const int row0 = blockIdx.x * 64 + w * 16;
    const float* ap = feat + (size_t)(row0 + r) * CIN + g * 8;

    f32x4 acc[4] = {};
    #pragma unroll
    for (int ks = 0; ks < 8; ++ks) {
        f32x4 a0 = *(const f32x4*)(ap + ks * 32);
        f32x4 a1 = *(const f32x4*)(ap + ks * 32 + 4);
        bf16x8 af;
        #pragma unroll
        for (int j = 0; j < 4; ++j) { af[j] = f2bf(a0[j]); af[4 + j] = f2bf(a1[j]); }
        #pragma unroll
        for (int ct = 0; ct < 4; ++ct) {
            bf16x8 bf = *(const bf16x8*)&w1t[ct * 16 + r][ks * 32 + g * 8];
            acc[ct] = mfma16(af, bf, acc[ct]);
        }
    }
    #pragma unroll
    for (int ct = 0; ct < 4; ++ct)
        #pragma unroll
        for (int j = 0; j < 4; ++j) {
            float v = acc[ct][j];
            o1[w * 16 + g * 4 + j][ct * 16 + r] = f2bf(v > 0.f ? v : 0.f);
        }
    __syncthreads();
    #pragma unroll
    for (int i = 0; i < 2; ++i) {
        int v = t + 256 * i; int row = v >> 3, c8 = v & 7;
        *(bf16x8*)&x1[(size_t)(blockIdx.x * 64 + row) * CMID + c8 * 8] =
            *(const bf16x8*)&o1[row][c8 * 8];
    }
}

// ---------------- K23P: persistent-block fused conv2+relu+conv3+residual+relu
// 512 thr, 1 block/CU (LDS 138 KB). All weights LDS-resident; after one initial
// barrier, waves run fully independently (no inter-wave sync at all).
__global__ __launch_bounds__(512) void k23_persist(const short* __restrict__ x1,
                                                   const short* __restrict__ W2T,
                                                   const short* __restrict__ W3T,
                                                   const int* __restrict__ nbr,
                                                   const float* __restrict__ feat,
                                                   float* __restrict__ out) {
    __shared__ short w2t[9][64][72];   // 82.9 KB, all 9 offsets
    __shared__ short w3t[256][72];     // 36.9 KB, full W3^T
    __shared__ short sc[8][16][72];    // 18.4 KB, per-wave scratch (o2 / ot alias)

    const int t = threadIdx.x;
    const int lane = t & 63, wv = t >> 6;
    const int r = lane & 15, g = lane >> 4;

    // ---- stage ALL weights once per block (256 blocks total, not 3125)
    #pragma unroll
    for (int kk = 0; kk < 9; ++kk) {
        bf16x8 v = *(const bf16x8*)(W2T + kk * 4096 + t * 8);
        *(bf16x8*)&w2t[kk][t >> 3][(t & 7) * 8] = v;
    }
    #pragma unroll
    for (int i = 0; i < 4; ++i) {
        bf16x8 v = *(const bf16x8*)(W3T + i * 4096 + t * 8);
        *(bf16x8*)&w3t[i * 64 + (t >> 3)][(t & 7) * 8] = v;
    }
    __syncthreads();   // last barrier in the kernel

    auto ot = reinterpret_cast<float(*)[36]>(&sc[wv][0][0]);   // [16][36] f32 view

    const int ustart = blockIdx.x * 49;
    const int uend = (ustart + 49 < UNITS) ? ustart + 49 : UNITS;
    for (int u = ustart + wv; u < uend; u += 8) {
        const int site0 = u * 16;
        const int site = site0 + r;

        int idx9[9];
        #pragma unroll
        for (int kk = 0; kk < 9; ++kk) idx9[kk] = nbr[site * 9 + kk];

        // rolling depth-4 gather pipeline, never barrier-gated
        bf16x8 ga[4], gb[4];
        #pragma unroll
        for (int p = 0; p < 4; ++p) {
            ga[p] = (bf16x8){}; gb[p] = (bf16x8){};
            int ii = idx9[p];
            if (ii >= 0) { const short* gp = x1 + (size_t)ii * CMID + g * 8;
                           ga[p] = *(const bf16x8*)gp; gb[p] = *(const bf16x8*)(gp + 32); }
        }

        f32x4 acc2[4] = {};
        #pragma unroll
        for (int kk = 0; kk < 9; ++kk) {
            const int cur = kk & 3;
            bf16x8 a0 = ga[cur], a1 = gb[cur];
            if (kk + 4 < 9) {
                int ii = idx9[kk + 4];
                bf16x8 n0 = {}, n1 = {};
                if (ii >= 0) { const short* gp = x1 + (size_t)ii * CMID + g * 8;
                               n0 = *(const bf16x8*)gp; n1 = *(const bf16x8*)(gp + 32); }
                ga[cur] = n0; gb[cur] = n1;
            }
            #pragma unroll
            for (int ct = 0; ct < 4; ++ct) {
                bf16x8 b0 = *(const bf16x8*)&w2t[kk][ct * 16 + r][g * 8];
                bf16x8 b1 = *(const bf16x8*)&w2t[kk][ct * 16 + r][32 + g * 8];
                acc2[ct] = mfma16(a0, b0, acc2[ct]);
                acc2[ct] = mfma16(a1, b1, acc2[ct]);
            }
        }

        // wave-private x2 bounce (C-layout -> A-fragments)
        #pragma unroll
        for (int ct = 0; ct < 4; ++ct)
            #pragma unroll
            for (int j = 0; j < 4; ++j) {
                float v = acc2[ct][j];
                sc[wv][g * 4 + j][ct * 16 + r] = f2bf(v > 0.f ? v : 0.f);
            }
        asm volatile("s_waitcnt lgkmcnt(0)" ::: "memory");
        bf16x8 A0 = *(const bf16x8*)&sc[wv][r][g * 8];
        bf16x8 A1 = *(const bf16x8*)&sc[wv][r][32 + g * 8];
        asm volatile("s_waitcnt lgkmcnt(0)" ::: "memory");  // A0/A1 landed before ot reuse

        // conv3: all 256 cols at once (acc3[16]; 2 waves/SIMD -> no VGPR pressure)
        f32x4 acc3[16];
        #pragma unroll
        for (int ct = 0; ct < 16; ++ct) {
            bf16x8 b0 = *(const bf16x8*)&w3t[ct * 16 + r][g * 8];
            bf16x8 b1 = *(const bf16x8*)&w3t[ct * 16 + r][32 + g * 8];
            f32x4 z = {};
            z = mfma16(A0, b0, z);
            acc3[ct] = mfma16(A1, b1, z);
        }

        // epilogue: 8 chunks of 32 cols, wave-private ot, coalesced f32x4 RMW
        #pragma unroll
        for (int c = 0; c < 8; ++c) {
            #pragma unroll
            for (int ci = 0; ci < 2; ++ci)
                #pragma unroll
                for (int j = 0; j < 4; ++j)
                    ot[g * 4 + j][ci * 16 + r] = acc3[c * 2 + ci][j];
            asm volatile("s_waitcnt lgkmcnt(0)" ::: "memory");
            #pragma unroll
            for (int i = 0; i < 2; ++i) {
                int v = lane + 64 * i;
                int row = v >> 3, c4 = v & 7;
                size_t o = (size_t)(site0 + row) * CIN + c * 32 + c4 * 4;
                f32x4 f = *(const f32x4*)&feat[o];       // L3-warm from K1
                f32x4 s = *(const f32x4*)&ot[row][c4 * 4];
                f32x4 res;
                #pragma unroll
                for (int j = 0; j < 4; ++j) { float x = s[j] + f[j]; res[j] = x > 0.f ? x : 0.f; }
                __builtin_nontemporal_store(res, (f32x4*)&out[o]);
            }
        }
    }
}

extern "C" void kernel_launch(void* const* d_in, const int* in_sizes, int n_in,
                              void* d_out, int out_size, void* d_ws, size_t ws_size,
                              hipStream_t stream) {
    const float* feat = (const float*)d_in[0];
    const float* W1   = (const float*)d_in[1];
    const float* W2   = (const float*)d_in[2];
    const float* W3   = (const float*)d_in[3];
    const int*   nbr  = (const int*)d_in[4];

    short* x1  = (short*)d_ws;                          // [N,64] bf16, 25.6 MB
    short* W2T = x1 + (size_t)N_SITES * CMID;           // [9][64][64] bf16
    short* W3T = W2T + KVOL * CMID * CMID;              // [256][64] bf16
    float* out = (float*)d_out;

    const int blocks = N_SITES / 64;                    // 3125
    hipLaunchKernelGGL(k1_conv1, dim3(blocks), dim3(256), 0, stream,
                       feat, W1, W2, W3, x1, W2T, W3T);
    hipLaunchKernelGGL(k23_persist, dim3(256), dim3(512), 0, stream,
                       x1, W2T, W3T, nbr, feat, out);
}